// Round 11
// baseline (471.747 us; speedup 1.0000x reference)
//
#include <hip/hip_runtime.h>
#include <hip/hip_bf16.h>

typedef short s16x8 __attribute__((ext_vector_type(8)));
typedef float f32x4 __attribute__((ext_vector_type(4)));
typedef unsigned short u16x8 __attribute__((ext_vector_type(8)));

__device__ __forceinline__ float bf2f(unsigned short u){
  union { unsigned int i; float f; } v; v.i = ((unsigned int)u) << 16; return v.f;
}
__device__ __forceinline__ unsigned short f2bf(float f){
  union { float f; unsigned int i; } v; v.f = f;
  unsigned int x = v.i;
  return (unsigned short)((x + 0x7fffu + ((x >> 16) & 1u)) >> 16);
}
__device__ __forceinline__ short f2bs(float f){
  union { __hip_bfloat16 h; short s; } u; u.h = __float2bfloat16(f); return u.s;
}
__device__ __forceinline__ s16x8 cvt8(f32x4 a, f32x4 b){
  s16x8 r;
  r[0]=f2bs(a[0]); r[1]=f2bs(a[1]); r[2]=f2bs(a[2]); r[3]=f2bs(a[3]);
  r[4]=f2bs(b[0]); r[5]=f2bs(b[1]); r[6]=f2bs(b[2]); r[7]=f2bs(b[3]);
  return r;
}

__device__ __forceinline__ void gload16(const void* g, void* l){
  __builtin_amdgcn_global_load_lds(
      (__attribute__((address_space(1))) void*)(g),
      (__attribute__((address_space(3))) void*)(l), 16, 0, 0);
}

// cast the 4 weight matrices (512x512 f32) to bf16 in one launch
__global__ __launch_bounds__(256) void cast_w(
    const float* __restrict__ w0, const float* __restrict__ w1,
    const float* __restrict__ w2, const float* __restrict__ w3,
    unsigned short* __restrict__ o0, unsigned short* __restrict__ o1,
    unsigned short* __restrict__ o2, unsigned short* __restrict__ o3)
{
  int g = blockIdx.x * 256 + threadIdx.x;
  int which = g >> 15;
  int off = (g & 32767) * 8;
  const float* src = which==0 ? w0 : which==1 ? w1 : which==2 ? w2 : w3;
  unsigned short* dst = which==0 ? o0 : which==1 ? o1 : which==2 ? o2 : o3;
  float4 a = *(const float4*)(src + off);
  float4 b = *(const float4*)(src + off + 4);
  u16x8 r;
  r[0]=f2bf(a.x); r[1]=f2bf(a.y); r[2]=f2bf(a.z); r[3]=f2bf(a.w);
  r[4]=f2bf(b.x); r[5]=f2bf(b.y); r[6]=f2bf(b.z); r[7]=f2bf(b.w);
  *(u16x8*)(dst + off) = r;
}

// Rolling-pipeline GEMM v3 (2 blocks/CU): out[M][512] = (A_f32 @ Wb^T + bias)*scale.
// Tile 128x128, 8 waves (4x2; wave tile 32x64), NT tiles/block, 4-slot LDS
// pipeline (64 KB total -> 2 blocks/CU). A: f32->reg (3 phases early)->cvt bf16
// ->swizzled ds_write (1 phase early). B: gload_lds w16 pre-swizzled source.
// vm-ops/stage = 3 -> counted vmcnt 6 steady / 38 boundary / 3,0 drain.
template<int OUT_BF16, int NT>
__global__ __launch_bounds__(512, 4) void gemm_v3(
    const float* __restrict__ A, const unsigned short* __restrict__ Wb,
    const float* __restrict__ bias, float scale, void* __restrict__ out_)
{
  __shared__ unsigned short As[4][128*32];   // 4 x 8 KB bf16
  __shared__ unsigned short Bs[4][128*32];   // 4 x 8 KB bf16  (total 64 KB)

  const int nwg = gridDim.x;                 // multiple of 8
  const int bid = blockIdx.x;
  const int wgid = (bid & 7) * (nwg >> 3) + (bid >> 3);  // bijective XCD swizzle
  const int bn = wgid & 3;                   // bn-inner: A-panel L2 reuse
  const int bmg = wgid >> 2;                 // NT tiles of 128 rows

  const int t = threadIdx.x;
  const int wid = t >> 6, lane = t & 63;
  const int wm = wid >> 1, wn = wid & 1;     // 4x2 waves; wave tile 32 x 64
  const int rl = lane & 15, kg = lane >> 4;

  const float* Ab0 = A + (size_t)bmg * (NT * 128) * 512;
  const unsigned short* Wgb = Wb + (size_t)bn * 128 * 512;

  const int ar4 = t >> 2, as4 = t & 3;       // A: row / logical 16B slot
  // B staging uses same decomp: col = t>>2, slot = t&3

  f32x4 areg[4][2];                          // A reg FIFO (static after unroll)

  #define STAGE(gph) do {                                                    \
    const int tau_=(gph)>>4, p_=(gph)&15, sl_=(gph)&3;                       \
    const int k0_=p_*32;                                                     \
    gload16(Wgb + (size_t)ar4*512 + k0_ + ((as4 ^ (ar4&3))<<3),              \
            &Bs[sl_][(size_t)t*8]);                                          \
    const float* Ab_ = Ab0 + (size_t)tau_*128*512 + (size_t)ar4*512 + k0_ + as4*8; \
    areg[sl_][0] = *(const f32x4*)(Ab_);                                     \
    areg[sl_][1] = *(const f32x4*)(Ab_ + 4);                                 \
  } while(0)

  #define AWRITE(gph) do {                                                   \
    const int sl_=(gph)&3;                                                   \
    *(s16x8*)&As[sl_][ar4*32 + ((as4 ^ (ar4&3))<<3)] =                       \
        cvt8(areg[sl_][0], areg[sl_][1]);                                    \
  } while(0)

  f32x4 acc[2][4];
  #pragma unroll
  for (int m=0;m<2;m++)
    #pragma unroll
    for (int n=0;n<4;n++) acc[m][n] = (f32x4){0.f,0.f,0.f,0.f};

  // prologue: 3 stages in flight; A(0) cvt+written (compiler waits its loads)
  STAGE(0); STAGE(1); STAGE(2);
  AWRITE(0);
  asm volatile("s_waitcnt lgkmcnt(0)" ::: "memory");

  for (int tau = 0; tau < NT; ++tau){
    #pragma unroll
    for (int p = 0; p < 16; ++p){
      if (NT > 1 && tau > 0 && p < 3)
        asm volatile("s_waitcnt vmcnt(38)" ::: "memory");  // 32 stores + 2 stages
      else if (tau == NT-1 && p == 14)
        asm volatile("s_waitcnt vmcnt(3)" ::: "memory");
      else if (tau == NT-1 && p == 15)
        asm volatile("s_waitcnt vmcnt(0)" ::: "memory");
      else
        asm volatile("s_waitcnt vmcnt(6)" ::: "memory");   // 2 stages in flight
      asm volatile("s_barrier" ::: "memory");

      const int sl = p & 3;
      s16x8 af[2], bw[4];
      #pragma unroll
      for (int m=0;m<2;m++){
        const int row = wm*32 + m*16 + rl;
        af[m] = *(const s16x8*)&As[sl][row*32 + ((kg ^ (row&3)) << 3)];
      }
      #pragma unroll
      for (int n=0;n<4;n++){
        const int col = wn*64 + n*16 + rl;
        bw[n] = *(const s16x8*)&Bs[sl][col*32 + ((kg ^ (col&3)) << 3)];
      }

      { const int gph = tau*16 + p + 3; if (gph < NT*16) STAGE(gph); }
      { const int gw  = tau*16 + p + 1; if (gw  < NT*16) AWRITE(gw); }

      __builtin_amdgcn_s_setprio(1);
      #pragma unroll
      for (int m=0;m<2;m++)
        #pragma unroll
        for (int n=0;n<4;n++)
          acc[m][n] = __builtin_amdgcn_mfma_f32_16x16x32_bf16(af[m], bw[n], acc[m][n], 0, 0, 0);
      __builtin_amdgcn_s_setprio(0);

      if (p == 15){
        #pragma unroll
        for (int n=0;n<4;n++){
          const int gcol = bn*128 + wn*64 + n*16 + rl;
          const float bv = bias[gcol];
          #pragma unroll
          for (int m=0;m<2;m++){
            const int growb = (bmg*NT + tau)*128 + wm*32 + m*16 + kg*4;
            #pragma unroll
            for (int r=0;r<4;r++){
              float v = (acc[m][n][r] + bv) * scale;
              size_t idx = (size_t)(growb + r) * 512 + gcol;
              if (OUT_BF16) ((unsigned short*)out_)[idx] = f2bf(v);
              else          ((float*)out_)[idx] = v;
            }
            acc[m][n] = (f32x4){0.f,0.f,0.f,0.f};
          }
        }
      }

      asm volatile("s_waitcnt lgkmcnt(0)" ::: "memory");   // my ds_write visible
      asm volatile("s_barrier" ::: "memory");
    }
  }
  #undef STAGE
  #undef AWRITE
}

// partial scores over one ww-chunk: part[wwc][b*512+dd][m] = sum_{ww in chunk} Qp[b,ww,dd]*Kp[b,ww,m,dd]
__global__ __launch_bounds__(256) void scores_kernel(
    const float* __restrict__ Qp, const unsigned short* __restrict__ Kp,
    float* __restrict__ part)
{
  const int wwc = blockIdx.x, ddt = blockIdx.y, b = blockIdx.z;
  const int ww0 = wwc*64, dd0 = ddt*64;
  __shared__ float qs[64][64];
  const int t = threadIdx.x;
  {
    const int dd = t & 63, wbase = t >> 6;
    #pragma unroll
    for (int i=0;i<16;i++){
      int ww = wbase + i*4;
      qs[ww][dd] = Qp[(size_t)(b*512 + ww0 + ww)*512 + dd0 + dd];
    }
  }
  __syncthreads();
  const int g = t & 7, mr = t >> 3;
  float acc[2][8];
  #pragma unroll
  for (int r=0;r<2;r++)
    #pragma unroll
    for (int j=0;j<8;j++) acc[r][j] = 0.f;

  for (int ww=0; ww<64; ww++){
    float4 q0 = *(const float4*)&qs[ww][g*8];
    float4 q1 = *(const float4*)&qs[ww][g*8+4];
    float qv[8] = {q0.x,q0.y,q0.z,q0.w,q1.x,q1.y,q1.z,q1.w};
    #pragma unroll
    for (int r=0;r<2;r++){
      const int m = mr + r*32;
      u16x8 kv = *(const u16x8*)&Kp[((size_t)(b*512 + ww0 + ww)*64 + m)*512 + dd0 + g*8];
      #pragma unroll
      for (int j=0;j<8;j++) acc[r][j] += qv[j] * bf2f(kv[j]);
    }
  }
  #pragma unroll
  for (int r=0;r<2;r++){
    const int m = mr + r*32;
    #pragma unroll
    for (int j=0;j<8;j++){
      const int dd = dd0 + g*8 + j;
      part[(size_t)wwc*131072 + (size_t)(b*512 + dd)*64 + m] = acc[r][j];
    }
  }
}

__global__ __launch_bounds__(256) void softmax_kernel(
    const float* __restrict__ part, float* __restrict__ attn)
{
  const int row = blockIdx.x*4 + (threadIdx.x >> 6);
  const int m = threadIdx.x & 63;
  float v = 0.f;
  #pragma unroll
  for (int c=0;c<8;c++) v += part[(size_t)c*131072 + (size_t)row*64 + m];
  float mx = v;
  #pragma unroll
  for (int o=32;o>=1;o>>=1) mx = fmaxf(mx, __shfl_xor(mx, o));
  float e = __expf(v - mx);
  float s = e;
  #pragma unroll
  for (int o=32;o>=1;o>>=1) s += __shfl_xor(s, o);
  attn[(size_t)row*64 + m] = e / s;
}

__global__ __launch_bounds__(256) void pv_kernel(
    const float* __restrict__ attn, const unsigned short* __restrict__ Vp,
    float* __restrict__ att_out)
{
  const int wwc = blockIdx.x, ddt = blockIdx.y, b = blockIdx.z;
  const int ww0 = wwc*64, dd0 = ddt*64;
  __shared__ float as_[64][72];
  const int t = threadIdx.x;
  {
    const int m = t & 63, dbase = t >> 6;
    #pragma unroll
    for (int i=0;i<16;i++){
      int dd = dbase + i*4;
      as_[m][dd] = attn[(size_t)(b*512 + dd0 + dd)*64 + m];
    }
  }
  __syncthreads();
  const int g = t & 7, wr = t >> 3;
  float acc[2][8];
  #pragma unroll
  for (int r=0;r<2;r++)
    #pragma unroll
    for (int j=0;j<8;j++) acc[r][j] = 0.f;

  for (int m=0;m<64;m++){
    float4 a0 = *(const float4*)&as_[m][g*8];
    float4 a1 = *(const float4*)&as_[m][g*8+4];
    float av[8] = {a0.x,a0.y,a0.z,a0.w,a1.x,a1.y,a1.z,a1.w};
    #pragma unroll
    for (int r=0;r<2;r++){
      const int ww = wr + r*32;
      u16x8 vv = *(const u16x8*)&Vp[((size_t)(b*512 + ww0 + ww)*64 + m)*512 + dd0 + g*8];
      #pragma unroll
      for (int j=0;j<8;j++) acc[r][j] += av[j] * bf2f(vv[j]);
    }
  }
  #pragma unroll
  for (int r=0;r<2;r++){
    const int ww = ww0 + wr + r*32;
    float4 o0 = {acc[r][0],acc[r][1],acc[r][2],acc[r][3]};
    float4 o1 = {acc[r][4],acc[r][5],acc[r][6],acc[r][7]};
    float* dst = &att_out[(size_t)(ww*4 + b)*512 + dd0 + g*8];
    *(float4*)dst = o0;
    *(float4*)(dst+4) = o1;
  }
}

extern "C" void kernel_launch(void* const* d_in, const int* in_sizes, int n_in,
                              void* d_out, int out_size, void* d_ws, size_t ws_size,
                              hipStream_t stream) {
  const float* Q  = (const float*)d_in[0];
  const float* K  = (const float*)d_in[1];
  const float* V  = (const float*)d_in[2];
  const float* Wq = (const float*)d_in[3];
  const float* bq = (const float*)d_in[4];
  const float* Wk = (const float*)d_in[5];
  const float* bk = (const float*)d_in[6];
  const float* Wv = (const float*)d_in[7];
  const float* bv = (const float*)d_in[8];
  const float* Wp = (const float*)d_in[9];
  const float* bp = (const float*)d_in[10];
  float* out = (float*)d_out;

  char* ws = (char*)d_ws;
  float* Qp       = (float*)(ws);                       // 4 MiB
  float* part     = (float*)(ws + ((size_t)4<<20));     // 4 MiB (reused as att_out)
  float* att_out  = part;
  float* attn     = (float*)(ws + ((size_t)8<<20));     // 0.5 MiB
  unsigned short* Wqb = (unsigned short*)(ws + ((size_t)9<<20));
  unsigned short* Wkb = Wqb + 262144;
  unsigned short* Wvb = Wkb + 262144;
  unsigned short* Wpb = Wvb + 262144;                   // 2 MiB total
  unsigned short* KVp = (unsigned short*)(ws + ((size_t)11<<20)); // 128 MiB

  const float qscale = 0.044194173824159223f;  // 1/sqrt(512)

  cast_w<<<512, 256, 0, stream>>>(Wq, Wk, Wv, Wp, Wqb, Wkb, Wvb, Wpb);

  // Q projection (+bias, /sqrt(d)) -> f32   (16 m-tiles x 4 bn = 64 blocks)
  gemm_v3<0,1><<<64, 512, 0, stream>>>(Q, Wqb, bq, qscale, Qp);
  // K projection -> bf16  (1024 tiles / NT=8 x 4 bn = 512 blocks)
  gemm_v3<1,8><<<512, 512, 0, stream>>>(K, Wkb, bk, 1.f, KVp);
  scores_kernel<<<dim3(8,8,4), 256, 0, stream>>>(Qp, KVp, part);
  softmax_kernel<<<512, 256, 0, stream>>>(part, attn);
  // V projection reuses KVp (stream-ordered after scores)
  gemm_v3<1,8><<<512, 512, 0, stream>>>(V, Wvb, bv, 1.f, KVp);
  pv_kernel<<<dim3(8,8,4), 256, 0, stream>>>(attn, KVp, att_out);
  // output projection -> d_out   (16 m-tiles x 4 bn = 64 blocks)
  gemm_v3<0,1><<<64, 512, 0, stream>>>(att_out, Wpb, bp, 1.f, out);
}

// Round 12
// 430.076 us; speedup vs baseline: 1.0969x; 1.0969x over previous
//
#include <hip/hip_runtime.h>
#include <hip/hip_bf16.h>

typedef short s16x8 __attribute__((ext_vector_type(8)));
typedef float f32x4 __attribute__((ext_vector_type(4)));
typedef unsigned short u16x8 __attribute__((ext_vector_type(8)));

__device__ __forceinline__ float bf2f(unsigned short u){
  union { unsigned int i; float f; } v; v.i = ((unsigned int)u) << 16; return v.f;
}
__device__ __forceinline__ unsigned short f2bf(float f){
  union { float f; unsigned int i; } v; v.f = f;
  unsigned int x = v.i;
  return (unsigned short)((x + 0x7fffu + ((x >> 16) & 1u)) >> 16);
}
__device__ __forceinline__ short f2bs(float f){
  union { __hip_bfloat16 h; short s; } u; u.h = __float2bfloat16(f); return u.s;
}
__device__ __forceinline__ s16x8 cvt8(f32x4 a, f32x4 b){
  s16x8 r;
  r[0]=f2bs(a[0]); r[1]=f2bs(a[1]); r[2]=f2bs(a[2]); r[3]=f2bs(a[3]);
  r[4]=f2bs(b[0]); r[5]=f2bs(b[1]); r[6]=f2bs(b[2]); r[7]=f2bs(b[3]);
  return r;
}

__device__ __forceinline__ void gload16(const void* g, void* l){
  __builtin_amdgcn_global_load_lds(
      (__attribute__((address_space(1))) void*)(g),
      (__attribute__((address_space(3))) void*)(l), 16, 0, 0);
}

// cast the 4 weight matrices (512x512 f32) to bf16 in one launch
__global__ __launch_bounds__(256) void cast_w(
    const float* __restrict__ w0, const float* __restrict__ w1,
    const float* __restrict__ w2, const float* __restrict__ w3,
    unsigned short* __restrict__ o0, unsigned short* __restrict__ o1,
    unsigned short* __restrict__ o2, unsigned short* __restrict__ o3)
{
  int g = blockIdx.x * 256 + threadIdx.x;
  int which = g >> 15;
  int off = (g & 32767) * 8;
  const float* src = which==0 ? w0 : which==1 ? w1 : which==2 ? w2 : w3;
  unsigned short* dst = which==0 ? o0 : which==1 ? o1 : which==2 ? o2 : o3;
  float4 a = *(const float4*)(src + off);
  float4 b = *(const float4*)(src + off + 4);
  u16x8 r;
  r[0]=f2bf(a.x); r[1]=f2bf(a.y); r[2]=f2bf(a.z); r[3]=f2bf(a.w);
  r[4]=f2bf(b.x); r[5]=f2bf(b.y); r[6]=f2bf(b.z); r[7]=f2bf(b.w);
  *(u16x8*)(dst + off) = r;
}

// R8 rolling-pipeline GEMM (best known): out[M][512] = (A_f32 @ Wb^T + bias)*scale.
// 512 thr (8 waves, 4x2), tile 128x256, NT M-tiles/block, 4-slot LDS pipeline.
template<int OUT_BF16, int NT>
__global__ __launch_bounds__(512, 1) void gemm_mt(
    const float* __restrict__ A, const unsigned short* __restrict__ Wb,
    const float* __restrict__ bias, float scale, void* __restrict__ out_)
{
  __shared__ float          As[4][128*32];   // 4 x 16KB
  __shared__ unsigned short Bs[4][256*32];   // 4 x 16KB  (total 128KB)

  const int nwg = gridDim.x;                 // multiple of 8
  const int bid = blockIdx.x;
  const int wgid = (bid & 7) * (nwg >> 3) + (bid >> 3);  // bijective XCD swizzle
  const int bn = wgid & 1;
  const int bmg = wgid >> 1;

  const int t = threadIdx.x;
  const int wid = t >> 6, lane = t & 63;
  const int wm = wid >> 1, wn = wid & 1;     // 4x2 waves; wave tile 32 x 128
  const int rl = lane & 15, kg = lane >> 4;

  const float* Ab0 = A + (size_t)bmg * (NT * 128) * 512;
  const unsigned short* Wgb = Wb + (size_t)bn * 256 * 512;

  const int l3 = lane >> 3, l7 = lane & 7;   // A: row-sub / phys 16B slot
  const int l2 = lane >> 2, lb3 = lane & 3;  // B: col-sub / phys 16B slot

  #define STAGE(gph) do {                                                    \
    const int tau_ = (gph) >> 4, p_ = (gph) & 15, sl_ = (gph) & 3;           \
    const int k0_ = p_ * 32;                                                 \
    const float* Abase_ = Ab0 + (size_t)tau_ * 128 * 512;                    \
    _Pragma("unroll")                                                        \
    for (int j = 0; j < 2; ++j){                                             \
      int arow = j*64 + wid*8 + l3;                                          \
      gload16(Abase_ + (size_t)arow*512 + k0_ + ((l7 ^ l3) << 2),            \
              &As[sl_][(j*64 + wid*8)*32]);                                  \
      int bcol = j*128 + wid*16 + l2;                                        \
      gload16(Wgb + (size_t)bcol*512 + k0_ + ((lb3 ^ (l2&3)) << 3),          \
              &Bs[sl_][(j*128 + wid*16)*32]);                                \
    }                                                                        \
  } while(0)

  f32x4 acc[2][8];
  #pragma unroll
  for (int m=0;m<2;m++)
    #pragma unroll
    for (int n=0;n<8;n++) acc[m][n] = (f32x4){0.f,0.f,0.f,0.f};

  STAGE(0); STAGE(1); STAGE(2);

  for (int tau = 0; tau < NT; ++tau){
    #pragma unroll
    for (int p = 0; p < 16; ++p){
      if (NT > 1 && tau > 0 && p < 3)
        asm volatile("s_waitcnt vmcnt(63)" ::: "memory");
      else if (tau == NT-1 && p == 14)
        asm volatile("s_waitcnt vmcnt(4)" ::: "memory");
      else if (tau == NT-1 && p == 15)
        asm volatile("s_waitcnt vmcnt(0)" ::: "memory");
      else
        asm volatile("s_waitcnt vmcnt(8)" ::: "memory");
      asm volatile("s_barrier" ::: "memory");

      const int sl = p & 3;
      const float* ah = &As[sl][0];
      const unsigned short* bh = &Bs[sl][0];

      s16x8 af[2], bw[8];
      #pragma unroll
      for (int m=0;m<2;m++){
        const int row = wm*32 + m*16 + rl;
        f32x4 x0 = *(const f32x4*)(ah + row*32 + (((2*kg  ) ^ (row&7)) << 2));
        f32x4 x1 = *(const f32x4*)(ah + row*32 + (((2*kg+1) ^ (row&7)) << 2));
        af[m] = cvt8(x0, x1);
      }
      #pragma unroll
      for (int n=0;n<8;n++){
        const int col = wn*128 + n*16 + rl;
        bw[n] = *(const s16x8*)(bh + col*32 + ((kg ^ (col&3)) << 3));
      }

      { const int gph = tau*16 + p + 3; if (gph < NT*16) STAGE(gph); }

      __builtin_amdgcn_s_setprio(1);
      #pragma unroll
      for (int m=0;m<2;m++)
        #pragma unroll
        for (int n=0;n<8;n++)
          acc[m][n] = __builtin_amdgcn_mfma_f32_16x16x32_bf16(af[m], bw[n], acc[m][n], 0, 0, 0);
      __builtin_amdgcn_s_setprio(0);

      if (p == 15){
        #pragma unroll
        for (int n=0;n<8;n++){
          const int gcol = bn*256 + wn*128 + n*16 + rl;
          const float bv = bias[gcol];
          #pragma unroll
          for (int m=0;m<2;m++){
            const int growb = (bmg*NT + tau)*128 + wm*32 + m*16 + kg*4;
            #pragma unroll
            for (int r=0;r<4;r++){
              float v = (acc[m][n][r] + bv) * scale;
              size_t idx = (size_t)(growb + r) * 512 + gcol;
              if (OUT_BF16) ((unsigned short*)out_)[idx] = f2bf(v);
              else          ((float*)out_)[idx] = v;
            }
            acc[m][n] = (f32x4){0.f,0.f,0.f,0.f};
          }
        }
      }

      asm volatile("s_barrier" ::: "memory");
    }
  }
  #undef STAGE
}

// scores partials: part[wwc][b*512+dd][m] = sum_{ww in chunk} Qp[b,ww,dd]*Kp[b,ww,m,dd]
__global__ __launch_bounds__(256) void scores_kernel(
    const float* __restrict__ Qp, const unsigned short* __restrict__ Kp,
    float* __restrict__ part)
{
  const int wwc = blockIdx.x, ddt = blockIdx.y, b = blockIdx.z;
  const int ww0 = wwc*64, dd0 = ddt*64;
  __shared__ float qs[64][64];
  const int t = threadIdx.x;
  {
    const int dd = t & 63, wbase = t >> 6;
    #pragma unroll
    for (int i=0;i<16;i++){
      int ww = wbase + i*4;
      qs[ww][dd] = Qp[(size_t)(b*512 + ww0 + ww)*512 + dd0 + dd];
    }
  }
  __syncthreads();
  const int g = t & 7, mr = t >> 3;
  float acc[2][8];
  #pragma unroll
  for (int r=0;r<2;r++)
    #pragma unroll
    for (int j=0;j<8;j++) acc[r][j] = 0.f;

  for (int ww=0; ww<64; ww++){
    float4 q0 = *(const float4*)&qs[ww][g*8];
    float4 q1 = *(const float4*)&qs[ww][g*8+4];
    float qv[8] = {q0.x,q0.y,q0.z,q0.w,q1.x,q1.y,q1.z,q1.w};
    #pragma unroll
    for (int r=0;r<2;r++){
      const int m = mr + r*32;
      u16x8 kv = *(const u16x8*)&Kp[((size_t)(b*512 + ww0 + ww)*64 + m)*512 + dd0 + g*8];
      #pragma unroll
      for (int j=0;j<8;j++) acc[r][j] += qv[j] * bf2f(kv[j]);
    }
  }
  #pragma unroll
  for (int r=0;r<2;r++){
    const int m = mr + r*32;
    #pragma unroll
    for (int j=0;j<8;j++){
      const int dd = dd0 + g*8 + j;
      part[(size_t)wwc*131072 + (size_t)(b*512 + dd)*64 + m] = acc[r][j];
    }
  }
}

__global__ __launch_bounds__(256) void softmax_kernel(
    const float* __restrict__ part, float* __restrict__ attn)
{
  const int row = blockIdx.x*4 + (threadIdx.x >> 6);
  const int m = threadIdx.x & 63;
  float v = 0.f;
  #pragma unroll
  for (int c=0;c<8;c++) v += part[(size_t)c*131072 + (size_t)row*64 + m];
  float mx = v;
  #pragma unroll
  for (int o=32;o>=1;o>>=1) mx = fmaxf(mx, __shfl_xor(mx, o));
  float e = __expf(v - mx);
  float s = e;
  #pragma unroll
  for (int o=32;o>=1;o>>=1) s += __shfl_xor(s, o);
  attn[(size_t)row*64 + m] = e / s;
}

// seed att_out with the V bias (sum_m attn = 1): att_out[r][dd] = bv[dd]
__global__ __launch_bounds__(256) void att_init(
    const float* __restrict__ bv, float* __restrict__ att_out)
{
  int el = blockIdx.x*256 + threadIdx.x;     // 1M elements
  att_out[el] = bv[el & 511];
}

// BigW[b][dd][m*512+c] = attn[b,dd,m] * Wv[dd,c]  (bf16, one rounding from f32 Wv)
__global__ __launch_bounds__(256) void bigw_build(
    const float* __restrict__ attn, const float* __restrict__ Wv,
    unsigned short* __restrict__ BigW)
{
  const int row = blockIdx.x;                // b*512+dd, 2048 blocks
  const int dd = row & 511;
  const int t = threadIdx.x;
  __shared__ float asm_[64];
  __shared__ float wvs[512];
  if (t < 64) asm_[t] = attn[(size_t)row*64 + t];
  #pragma unroll
  for (int i=0;i<2;i++) wvs[i*256+t] = Wv[(size_t)dd*512 + i*256 + t];
  __syncthreads();
  unsigned short* dst = BigW + (size_t)row*32768;
  #pragma unroll
  for (int i=0;i<16;i++){
    int e = i*2048 + t*8;
    int m = e >> 9, c = e & 511;
    float a = asm_[m];
    u16x8 r;
    #pragma unroll
    for (int j=0;j<8;j++) r[j] = f2bf(a * wvs[c+j]);
    *(u16x8*)(dst + e) = r;
  }
}

// Fused PV GEMM: att_out[(w*4+b)][dd] += sum_k V[b,w,k] * BigW[b,dd,k], K=32768
// split-K 16 chunks of 2048 (64 phases). 512 thr, tile 128x256, R8 pipeline.
__global__ __launch_bounds__(512, 1) void gemm_pv(
    const float* __restrict__ V, const unsigned short* __restrict__ BigW,
    float* __restrict__ att_out)
{
  __shared__ float          As[4][128*32];   // 4 x 16KB
  __shared__ unsigned short Bs[4][256*32];   // 4 x 16KB

  const int nwg = gridDim.x;                 // 512
  const int bid = blockIdx.x;
  const int wgid = (bid & 7) * (nwg >> 3) + (bid >> 3);
  const int bn = wgid & 1;                   // dd half (256)
  const int mt = (wgid >> 1) & 3;            // w quarter (128)
  const int b  = (wgid >> 3) & 3;            // batch
  const int s  = wgid >> 5;                  // split-K chunk (2048 k)

  const int t = threadIdx.x;
  const int wid = t >> 6, lane = t & 63;
  const int wm = wid >> 1, wn = wid & 1;     // 4x2 waves; wave tile 32 x 128
  const int rl = lane & 15, kg = lane >> 4;

  const float* Ab = V + (size_t)b*512*32768 + (size_t)mt*128*32768 + s*2048;
  const unsigned short* Bb = BigW + (size_t)b*512*32768 + (size_t)bn*256*32768 + s*2048;

  const int l3 = lane >> 3, l7 = lane & 7;
  const int l2 = lane >> 2, lb3 = lane & 3;

  #define PSTAGE(ph) do {                                                    \
    const int sl_ = (ph) & 3;                                                \
    const int k0_ = (ph) * 32;                                               \
    _Pragma("unroll")                                                        \
    for (int j = 0; j < 2; ++j){                                             \
      int arow = j*64 + wid*8 + l3;                                          \
      gload16(Ab + (size_t)arow*32768 + k0_ + ((l7 ^ l3) << 2),              \
              &As[sl_][(j*64 + wid*8)*32]);                                  \
      int bcol = j*128 + wid*16 + l2;                                        \
      gload16(Bb + (size_t)bcol*32768 + k0_ + ((lb3 ^ (l2&3)) << 3),         \
              &Bs[sl_][(j*128 + wid*16)*32]);                                \
    }                                                                        \
  } while(0)

  f32x4 acc[2][8];
  #pragma unroll
  for (int m=0;m<2;m++)
    #pragma unroll
    for (int n=0;n<8;n++) acc[m][n] = (f32x4){0.f,0.f,0.f,0.f};

  PSTAGE(0); PSTAGE(1); PSTAGE(2);

  #pragma unroll 4
  for (int p = 0; p < 64; ++p){
    if (p == 62)      asm volatile("s_waitcnt vmcnt(4)" ::: "memory");
    else if (p == 63) asm volatile("s_waitcnt vmcnt(0)" ::: "memory");
    else              asm volatile("s_waitcnt vmcnt(8)" ::: "memory");
    asm volatile("s_barrier" ::: "memory");

    const int sl = p & 3;
    const float* ah = &As[sl][0];
    const unsigned short* bh = &Bs[sl][0];

    s16x8 af[2], bw[8];
    #pragma unroll
    for (int m=0;m<2;m++){
      const int row = wm*32 + m*16 + rl;
      f32x4 x0 = *(const f32x4*)(ah + row*32 + (((2*kg  ) ^ (row&7)) << 2));
      f32x4 x1 = *(const f32x4*)(ah + row*32 + (((2*kg+1) ^ (row&7)) << 2));
      af[m] = cvt8(x0, x1);
    }
    #pragma unroll
    for (int n=0;n<8;n++){
      const int col = wn*128 + n*16 + rl;
      bw[n] = *(const s16x8*)(bh + col*32 + ((kg ^ (col&3)) << 3));
    }

    if (p + 3 < 64) PSTAGE(p + 3);

    __builtin_amdgcn_s_setprio(1);
    #pragma unroll
    for (int m=0;m<2;m++)
      #pragma unroll
      for (int n=0;n<8;n++)
        acc[m][n] = __builtin_amdgcn_mfma_f32_16x16x32_bf16(af[m], bw[n], acc[m][n], 0, 0, 0);
    __builtin_amdgcn_s_setprio(0);

    asm volatile("s_barrier" ::: "memory");
  }
  #undef PSTAGE

  #pragma unroll
  for (int n=0;n<8;n++){
    const int gcol = bn*256 + wn*128 + n*16 + rl;
    #pragma unroll
    for (int m=0;m<2;m++){
      const int wrow = mt*128 + wm*32 + m*16 + kg*4;
      #pragma unroll
      for (int r=0;r<4;r++){
        size_t idx = (size_t)((wrow + r)*4 + b) * 512 + gcol;
        atomicAdd(&att_out[idx], acc[m][n][r]);
      }
    }
  }
}

extern "C" void kernel_launch(void* const* d_in, const int* in_sizes, int n_in,
                              void* d_out, int out_size, void* d_ws, size_t ws_size,
                              hipStream_t stream) {
  const float* Q  = (const float*)d_in[0];
  const float* K  = (const float*)d_in[1];
  const float* V  = (const float*)d_in[2];
  const float* Wq = (const float*)d_in[3];
  const float* bq = (const float*)d_in[4];
  const float* Wk = (const float*)d_in[5];
  const float* bk = (const float*)d_in[6];
  const float* Wv = (const float*)d_in[7];
  const float* bv = (const float*)d_in[8];
  const float* Wp = (const float*)d_in[9];
  const float* bp = (const float*)d_in[10];
  float* out = (float*)d_out;

  char* ws = (char*)d_ws;
  float* Qp       = (float*)(ws);                       // 4 MiB
  float* part     = (float*)(ws + ((size_t)4<<20));     // 4 MiB (reused as att_out)
  float* att_out  = part;
  float* attn     = (float*)(ws + ((size_t)8<<20));     // 0.5 MiB
  unsigned short* Wqb = (unsigned short*)(ws + ((size_t)9<<20));
  unsigned short* Wkb = Wqb + 262144;
  unsigned short* Wvb = Wkb + 262144;
  unsigned short* Wpb = Wvb + 262144;                   // 2 MiB total
  unsigned short* KVp = (unsigned short*)(ws + ((size_t)11<<20)); // 128 MiB (Kp, then BigW)
  unsigned short* BigW = KVp;

  const float qscale = 0.044194173824159223f;  // 1/sqrt(512)

  cast_w<<<512, 256, 0, stream>>>(Wq, Wk, Wv, Wp, Wqb, Wkb, Wvb, Wpb);

  // Q projection (+bias, /sqrt(d)) -> f32
  gemm_mt<0,1><<<32, 512, 0, stream>>>(Q, Wqb, bq, qscale, Qp);
  // K projection -> bf16
  gemm_mt<1,4><<<512, 512, 0, stream>>>(K, Wkb, bk, 1.f, KVp);
  scores_kernel<<<dim3(8,8,4), 256, 0, stream>>>(Qp, KVp, part);
  softmax_kernel<<<512, 256, 0, stream>>>(part, attn);
  // fused PV: att_out = bias + V @ BigW^T (BigW overwrites Kp after scores)
  att_init<<<4096, 256, 0, stream>>>(bv, att_out);
  bigw_build<<<2048, 256, 0, stream>>>(attn, Wv, BigW);
  gemm_pv<<<512, 512, 0, stream>>>(V, BigW, att_out);
  // output projection -> d_out
  gemm_mt<0,1><<<32, 512, 0, stream>>>(att_out, Wpb, bp, 1.f, out);
}

// Round 13
// 380.001 us; speedup vs baseline: 1.2414x; 1.1318x over previous
//
#include <hip/hip_runtime.h>
#include <hip/hip_bf16.h>

typedef short s16x8 __attribute__((ext_vector_type(8)));
typedef float f32x4 __attribute__((ext_vector_type(4)));
typedef unsigned short u16x8 __attribute__((ext_vector_type(8)));

__device__ __forceinline__ float bf2f(unsigned short u){
  union { unsigned int i; float f; } v; v.i = ((unsigned int)u) << 16; return v.f;
}
__device__ __forceinline__ unsigned short f2bf(float f){
  union { float f; unsigned int i; } v; v.f = f;
  unsigned int x = v.i;
  return (unsigned short)((x + 0x7fffu + ((x >> 16) & 1u)) >> 16);
}
__device__ __forceinline__ short f2bs(float f){
  union { __hip_bfloat16 h; short s; } u; u.h = __float2bfloat16(f); return u.s;
}
__device__ __forceinline__ s16x8 cvt8(f32x4 a, f32x4 b){
  s16x8 r;
  r[0]=f2bs(a[0]); r[1]=f2bs(a[1]); r[2]=f2bs(a[2]); r[3]=f2bs(a[3]);
  r[4]=f2bs(b[0]); r[5]=f2bs(b[1]); r[6]=f2bs(b[2]); r[7]=f2bs(b[3]);
  return r;
}

__device__ __forceinline__ void gload16(const void* g, void* l){
  __builtin_amdgcn_global_load_lds(
      (__attribute__((address_space(1))) void*)(g),
      (__attribute__((address_space(3))) void*)(l), 16, 0, 0);
}

// cast the 4 weight matrices (512x512 f32) to bf16 in one launch
__global__ __launch_bounds__(256) void cast_w(
    const float* __restrict__ w0, const float* __restrict__ w1,
    const float* __restrict__ w2, const float* __restrict__ w3,
    unsigned short* __restrict__ o0, unsigned short* __restrict__ o1,
    unsigned short* __restrict__ o2, unsigned short* __restrict__ o3)
{
  int g = blockIdx.x * 256 + threadIdx.x;
  int which = g >> 15;
  int off = (g & 32767) * 8;
  const float* src = which==0 ? w0 : which==1 ? w1 : which==2 ? w2 : w3;
  unsigned short* dst = which==0 ? o0 : which==1 ? o1 : which==2 ? o2 : o3;
  float4 a = *(const float4*)(src + off);
  float4 b = *(const float4*)(src + off + 4);
  u16x8 r;
  r[0]=f2bf(a.x); r[1]=f2bf(a.y); r[2]=f2bf(a.z); r[3]=f2bf(a.w);
  r[4]=f2bf(b.x); r[5]=f2bf(b.y); r[6]=f2bf(b.z); r[7]=f2bf(b.w);
  *(u16x8*)(dst + off) = r;
}

// m201-shaped engine: out[.][512] = (A_f32 @ B_bf16^T [+ bias]) * scale
// BK=64, 2-slot dbuf (128 KB LDS), tile 128x256, 8 waves 2x4 (wave tile 64x64).
// Per K-tile: {reads h0 | MFMA h0 | reads h1 | lgkm0 | BAR | stage T+2 | MFMA h1
//              | [epilogue] | vmcnt(8) | BAR}  -- one counted vmcnt per tile.
// A rows 256 B, 16-slot XOR; B rows 128 B, 8-slot XOR -> conflict-free b128.
// OUT_MODE: 0 = f32 store, 1 = bf16 store, 2 = f32 atomicAdd (bias ignored).
template<int OUT_MODE, int NT, int KT, int PV>
__global__ __launch_bounds__(512, 1) void gemm_k64(
    const float* __restrict__ A, const unsigned short* __restrict__ B,
    const float* __restrict__ bias, float scale, void* __restrict__ out_,
    int SA, int SB)
{
  __shared__ float          Af[2][128*64];     // 2 x 32 KB
  __shared__ unsigned short Bf[2][256*64];     // 2 x 32 KB   (total 128 KB)

  const int nwg = gridDim.x;                   // multiple of 8
  const int bid = blockIdx.x;
  const int wgid = (bid & 7) * (nwg >> 3) + (bid >> 3);  // bijective XCD swizzle

  const int t = threadIdx.x;
  const int wid = t >> 6, lane = t & 63;
  const int wm = wid >> 2, wn = wid & 3;       // 2x4 waves; wave tile 64x64
  const int rl = lane & 15, kg = lane >> 4;

  int bn, bmg = 0, mt = 0, b = 0;
  const float* Ab0;
  const unsigned short* Bb0;
  if (PV){
    bn = wgid & 1;
    mt = (wgid >> 1) & 3;
    b  = (wgid >> 3) & 3;
    const int sk = wgid >> 5;                  // split-K 0..7, 4096 k each
    Ab0 = A + (size_t)b*512*32768 + (size_t)mt*128*32768 + sk*4096;
    Bb0 = B + (size_t)b*512*32768 + (size_t)bn*256*32768 + sk*4096;
  } else {
    bn = wgid & 1;
    bmg = wgid >> 1;
    Ab0 = A + (size_t)bmg * (NT*128) * SA;
    Bb0 = B + (size_t)bn * 256 * SB;
  }

  // staging lane decomposition (linear LDS dest, pre-swizzled global source)
  const int jrowA = wid*4 + (lane >> 4);       // + j*32 ; A row
  const int aslot = lane & 15;                 // 16B slot within 256B row
  const int jcolB = wid*8 + (lane >> 3);       // + j*64 ; B col
  const int bslot = lane & 7;                  // 16B slot within 128B row

  #define STAGE(T_) do{                                                        \
    const int st_ = (T_) & 1;                                                  \
    const int kt_ = (T_) & (KT-1);                                             \
    const int tau_ = (T_) / KT;                                                \
    const float* As_ = Ab0 + (size_t)tau_*128*SA + kt_*64;                     \
    const unsigned short* Bs_ = Bb0 + kt_*64;                                  \
    _Pragma("unroll")                                                          \
    for (int j = 0; j < 4; ++j){                                               \
      int ar = j*32 + jrowA;                                                   \
      gload16(As_ + (size_t)ar*SA + ((aslot ^ (ar&15)) << 2),                  \
              &Af[st_][(j*8 + wid)*256]);                                      \
      int bc = j*64 + jcolB;                                                   \
      gload16(Bs_ + (size_t)bc*SB + ((bslot ^ (bc&7)) << 3),                   \
              &Bf[st_][(j*8 + wid)*512]);                                      \
    }                                                                          \
  }while(0)

  #define READS(sl_, h_, af_, bw_) do{                                         \
    _Pragma("unroll")                                                          \
    for (int m = 0; m < 4; ++m){                                               \
      const int r_ = wm*64 + m*16 + rl;                                        \
      const int s0_ = (h_)*8 + kg*2;                                           \
      f32x4 x0 = *(const f32x4*)&Af[sl_][r_*64 + ((s0_     ^ (r_&15)) << 2)];  \
      f32x4 x1 = *(const f32x4*)&Af[sl_][r_*64 + (((s0_+1) ^ (r_&15)) << 2)];  \
      af_[m] = cvt8(x0, x1);                                                   \
    }                                                                          \
    _Pragma("unroll")                                                          \
    for (int n = 0; n < 4; ++n){                                               \
      const int c_ = wn*64 + n*16 + rl;                                        \
      const int sb_ = (h_)*4 + kg;                                             \
      bw_[n] = *(const s16x8*)&Bf[sl_][c_*64 + ((sb_ ^ (c_&7)) << 3)];         \
    }                                                                          \
  }while(0)

  #define MFMA16(af_, bw_) do{                                                 \
    __builtin_amdgcn_s_setprio(1);                                             \
    _Pragma("unroll")                                                          \
    for (int m = 0; m < 4; ++m)                                                \
      _Pragma("unroll")                                                        \
      for (int n = 0; n < 4; ++n)                                              \
        acc[m][n] = __builtin_amdgcn_mfma_f32_16x16x32_bf16(af_[m], bw_[n], acc[m][n], 0, 0, 0); \
    __builtin_amdgcn_s_setprio(0);                                             \
  }while(0)

  f32x4 acc[4][4];
  #pragma unroll
  for (int m=0;m<4;m++)
    #pragma unroll
    for (int n=0;n<4;n++) acc[m][n] = (f32x4){0.f,0.f,0.f,0.f};

  const int TT = NT * KT;
  STAGE(0); STAGE(1);
  asm volatile("s_waitcnt vmcnt(8)" ::: "memory");   // tile 0 landed
  asm volatile("s_barrier" ::: "memory");

  #pragma unroll 2
  for (int T = 0; T < TT; ++T){
    const int sl = T & 1;
    s16x8 af0[4], bw0[4], af1[4], bw1[4];

    READS(sl, 0, af0, bw0);
    MFMA16(af0, bw0);
    READS(sl, 1, af1, bw1);

    asm volatile("s_waitcnt lgkmcnt(0)" ::: "memory");  // my slot-sl reads done
    asm volatile("s_barrier" ::: "memory");             // all waves' reads done

    if (T + 2 < TT) STAGE(T + 2);                       // safe: slot sl free

    MFMA16(af1, bw1);

    if ((T & (KT-1)) == KT-1){
      const int tau = T / KT;
      #pragma unroll
      for (int n=0;n<4;n++){
        const int gcol = bn*256 + wn*64 + n*16 + rl;
        float bv = 0.f;
        if (OUT_MODE != 2) bv = bias[gcol];
        #pragma unroll
        for (int m=0;m<4;m++){
          #pragma unroll
          for (int r=0;r<4;r++){
            const int lrow = wm*64 + m*16 + kg*4 + r;
            if (OUT_MODE == 2){
              const int w_ = mt*128 + lrow;
              atomicAdd(&((float*)out_)[(size_t)(w_*4 + b)*512 + gcol], acc[m][n][r]);
            } else {
              const int grow = (bmg*NT + tau)*128 + lrow;
              float v = (acc[m][n][r] + bv) * scale;
              size_t idx = (size_t)grow * 512 + gcol;
              if (OUT_MODE == 1) ((unsigned short*)out_)[idx] = f2bf(v);
              else               ((float*)out_)[idx] = v;
            }
          }
          acc[m][n] = (f32x4){0.f,0.f,0.f,0.f};
        }
      }
    }

    if (T + 2 < TT)      asm volatile("s_waitcnt vmcnt(8)" ::: "memory");
    else if (T + 1 < TT) asm volatile("s_waitcnt vmcnt(0)" ::: "memory");
    if (T + 1 < TT)      asm volatile("s_barrier" ::: "memory");
  }
  #undef STAGE
  #undef READS
  #undef MFMA16
}

// scores partials: part[wwc][b*512+dd][m] = sum_{ww in chunk} Qp[b,ww,dd]*Kp[b,ww,m,dd]
__global__ __launch_bounds__(256) void scores_kernel(
    const float* __restrict__ Qp, const unsigned short* __restrict__ Kp,
    float* __restrict__ part)
{
  const int wwc = blockIdx.x, ddt = blockIdx.y, b = blockIdx.z;
  const int ww0 = wwc*64, dd0 = ddt*64;
  __shared__ float qs[64][64];
  const int t = threadIdx.x;
  {
    const int dd = t & 63, wbase = t >> 6;
    #pragma unroll
    for (int i=0;i<16;i++){
      int ww = wbase + i*4;
      qs[ww][dd] = Qp[(size_t)(b*512 + ww0 + ww)*512 + dd0 + dd];
    }
  }
  __syncthreads();
  const int g = t & 7, mr = t >> 3;
  float acc[2][8];
  #pragma unroll
  for (int r=0;r<2;r++)
    #pragma unroll
    for (int j=0;j<8;j++) acc[r][j] = 0.f;

  for (int ww=0; ww<64; ww++){
    float4 q0 = *(const float4*)&qs[ww][g*8];
    float4 q1 = *(const float4*)&qs[ww][g*8+4];
    float qv[8] = {q0.x,q0.y,q0.z,q0.w,q1.x,q1.y,q1.z,q1.w};
    #pragma unroll
    for (int r=0;r<2;r++){
      const int m = mr + r*32;
      u16x8 kv = *(const u16x8*)&Kp[((size_t)(b*512 + ww0 + ww)*64 + m)*512 + dd0 + g*8];
      #pragma unroll
      for (int j=0;j<8;j++) acc[r][j] += qv[j] * bf2f(kv[j]);
    }
  }
  #pragma unroll
  for (int r=0;r<2;r++){
    const int m = mr + r*32;
    #pragma unroll
    for (int j=0;j<8;j++){
      const int dd = dd0 + g*8 + j;
      part[(size_t)wwc*131072 + (size_t)(b*512 + dd)*64 + m] = acc[r][j];
    }
  }
}

__global__ __launch_bounds__(256) void softmax_kernel(
    const float* __restrict__ part, float* __restrict__ attn)
{
  const int row = blockIdx.x*4 + (threadIdx.x >> 6);
  const int m = threadIdx.x & 63;
  float v = 0.f;
  #pragma unroll
  for (int c=0;c<8;c++) v += part[(size_t)c*131072 + (size_t)row*64 + m];
  float mx = v;
  #pragma unroll
  for (int o=32;o>=1;o>>=1) mx = fmaxf(mx, __shfl_xor(mx, o));
  float e = __expf(v - mx);
  float s = e;
  #pragma unroll
  for (int o=32;o>=1;o>>=1) s += __shfl_xor(s, o);
  attn[(size_t)row*64 + m] = e / s;
}

// seed att_out with the V bias (sum_m attn = 1): att_out[r][dd] = bv[dd]
__global__ __launch_bounds__(256) void att_init(
    const float* __restrict__ bv, float* __restrict__ att_out)
{
  int el = blockIdx.x*256 + threadIdx.x;     // 1M elements
  att_out[el] = bv[el & 511];
}

// BigW[b][dd][m*512+c] = attn[b,dd,m] * Wv[dd,c]  (bf16)
__global__ __launch_bounds__(256) void bigw_build(
    const float* __restrict__ attn, const float* __restrict__ Wv,
    unsigned short* __restrict__ BigW)
{
  const int row = blockIdx.x;                // b*512+dd, 2048 blocks
  const int dd = row & 511;
  const int t = threadIdx.x;
  __shared__ float asm_[64];
  __shared__ float wvs[512];
  if (t < 64) asm_[t] = attn[(size_t)row*64 + t];
  #pragma unroll
  for (int i=0;i<2;i++) wvs[i*256+t] = Wv[(size_t)dd*512 + i*256 + t];
  __syncthreads();
  unsigned short* dst = BigW + (size_t)row*32768;
  #pragma unroll
  for (int i=0;i<16;i++){
    int e = i*2048 + t*8;
    int m = e >> 9, c = e & 511;
    float a = asm_[m];
    u16x8 r;
    #pragma unroll
    for (int j=0;j<8;j++) r[j] = f2bf(a * wvs[c+j]);
    *(u16x8*)(dst + e) = r;
  }
}

extern "C" void kernel_launch(void* const* d_in, const int* in_sizes, int n_in,
                              void* d_out, int out_size, void* d_ws, size_t ws_size,
                              hipStream_t stream) {
  const float* Q  = (const float*)d_in[0];
  const float* K  = (const float*)d_in[1];
  const float* V  = (const float*)d_in[2];
  const float* Wq = (const float*)d_in[3];
  const float* bq = (const float*)d_in[4];
  const float* Wk = (const float*)d_in[5];
  const float* bk = (const float*)d_in[6];
  const float* Wv = (const float*)d_in[7];
  const float* bv = (const float*)d_in[8];
  const float* Wp = (const float*)d_in[9];
  const float* bp = (const float*)d_in[10];
  float* out = (float*)d_out;

  char* ws = (char*)d_ws;
  float* Qp       = (float*)(ws);                       // 4 MiB
  float* part     = (float*)(ws + ((size_t)4<<20));     // 4 MiB (reused as att_out)
  float* att_out  = part;
  float* attn     = (float*)(ws + ((size_t)8<<20));     // 0.5 MiB
  unsigned short* Wqb = (unsigned short*)(ws + ((size_t)9<<20));
  unsigned short* Wkb = Wqb + 262144;
  unsigned short* Wvb = Wkb + 262144;
  unsigned short* Wpb = Wvb + 262144;                   // 2 MiB total
  unsigned short* KVp = (unsigned short*)(ws + ((size_t)11<<20)); // 128 MiB (Kp, then BigW)
  unsigned short* BigW = KVp;

  const float qscale = 0.044194173824159223f;  // 1/sqrt(512)

  cast_w<<<512, 256, 0, stream>>>(Wq, Wk, Wv, Wp, Wqb, Wkb, Wvb, Wpb);

  // Q projection (+bias, /sqrt(d)) -> f32   (16 m-tiles x 2 bn = 32 blocks)
  gemm_k64<0,1,8,0><<<32, 512, 0, stream>>>(Q, Wqb, bq, qscale, Qp, 512, 512);
  // K projection -> bf16  (1024 m-tiles / NT=8 x 2 bn = 256 blocks, 1 round)
  gemm_k64<1,8,8,0><<<256, 512, 0, stream>>>(K, Wkb, bk, 1.f, KVp, 512, 512);
  scores_kernel<<<dim3(8,8,4), 256, 0, stream>>>(Qp, KVp, part);
  softmax_kernel<<<512, 256, 0, stream>>>(part, attn);
  // fused PV: att_out = bias + V @ BigW^T  (BigW overwrites Kp after scores)
  att_init<<<4096, 256, 0, stream>>>(bv, att_out);
  bigw_build<<<2048, 256, 0, stream>>>(attn, Wv, BigW);
  gemm_k64<2,1,64,1><<<256, 512, 0, stream>>>(V, BigW, bv, 1.f, att_out, 32768, 32768);
  // output projection -> d_out
  gemm_k64<0,1,8,0><<<32, 512, 0, stream>>>(att_out, Wpb, bp, 1.f, out, 512, 512);
}